// Round 3
// baseline (561.521 us; speedup 1.0000x reference)
//
#include <hip/hip_runtime.h>
#include <hip/hip_cooperative_groups.h>
#include <math.h>

namespace cg = cooperative_groups;

#define BB 2048
#define TT 200
#define BN_EPS 1e-3f
#define MASKV (-4294967295.0f)
#define INV_SQRTK 0.08838834764831845f

typedef short bfrag __attribute__((ext_vector_type(8)));
typedef float f32x4 __attribute__((ext_vector_type(4)));

__device__ __forceinline__ unsigned short f2b(float x) {
    union { float f; unsigned u; } v; v.f = x;
    unsigned r = (v.u + 0x7fffu + ((v.u >> 16) & 1u)) >> 16;
    return (unsigned short)r;
}
__device__ __forceinline__ float sigm(float x) { return 1.f / (1.f + __expf(-x)); }

// ---------------------------------------------------------------------------
// k0: weight prep.
//  W1pair[(j*128+k)*2+{0,1}] = { W1[(128+k)*80+j]-W1[(256+k)*80+j], W1[(384+k)*80+j] }
//  W1ac [k*80+j] = W1[k*80+j] + W1[(256+k)*80+j]
//  fc1WT[j*384+c] = fc1W[c*80+j] ; fc2WT[j*80+c] = fc2W[c*40+j]
// ---------------------------------------------------------------------------
__global__ __launch_bounds__(256) void k0_prep(
    const float* __restrict__ W1, const float* __restrict__ fc1W,
    const float* __restrict__ fc2W, float* __restrict__ prep)
{
    const int gid = blockIdx.x * 256 + threadIdx.x;
    const int stride = gridDim.x * 256;
    float* W1pair = prep;                 // 20480
    float* W1ac   = prep + 20480;         // 10240
    float* fc1WT  = prep + 30720;         // 30720
    float* fc2WT  = prep + 61440;         // 3200
    for (int i = gid; i < 10240; i += stride) {
        int j = i >> 7, k = i & 127;
        float wa = W1[k * 80 + j];
        float wb = W1[(128 + k) * 80 + j];
        float wc = W1[(256 + k) * 80 + j];
        float wd = W1[(384 + k) * 80 + j];
        W1pair[i * 2]     = wb - wc;
        W1pair[i * 2 + 1] = wd;
        W1ac[k * 80 + j]  = wa + wc;
    }
    for (int i = gid; i < 30720; i += stride) { int j = i / 384, c = i - j * 384; fc1WT[i] = fc1W[c * 80 + j]; }
    for (int i = gid; i < 3200;  i += stride) { int j = i / 80,  c = i - j * 80;  fc2WT[i] = fc2W[c * 40 + j]; }
}

// ---------------------------------------------------------------------------
// K1: DIN attention. 2048 blocks x 512 thr, ~77KB LDS -> 2 blocks/CU.
// Two M-passes of 112 rows; W2 fragments in registers; phase-D global gather.
// ---------------------------------------------------------------------------
__global__ __launch_bounds__(512, 4) void k1_attn(
    const int* __restrict__ item, const int* __restrict__ history,
    const int* __restrict__ length, const int* __restrict__ cate_list,
    const float* __restrict__ item_table, const float* __restrict__ cate_table,
    const float* __restrict__ W1pair, const float* __restrict__ W1ac,
    const float* __restrict__ b1, const float* __restrict__ W2,
    const float* __restrict__ b2, const float* __restrict__ W3,
    const float* __restrict__ b3,
    float* __restrict__ hist_attn, float* __restrict__ hstats)
{
    __shared__ __align__(16) unsigned short sA[112 * 136];   // 30464 B
    __shared__ __align__(16) unsigned short sW1[80 * 136];   // 21760 B
    __shared__ __align__(16) unsigned short sH1[112 * 104];  // 23296 B (aliased: sCp phase B, sPd phase D)
    __shared__ float sScore[256];                            // aliased: sQ (phases A/B)
    __shared__ float sCc[80];
    __shared__ int   sHist[TT], sCid[TT];
    __shared__ float sB2[48], sW3f[48];
    __shared__ float sRed[8], sMS[2], sB3v;

    float* const sQ  = sScore;        // 128 floats, dead before sScore zeroed
    float* const sCp = (float*)sH1;   // 480 floats, phase B only
    float* const sPd = (float*)sH1;   // 16*128 floats, phase D only

    const int b   = blockIdx.x;
    const int tid = threadIdx.x;
    const int it  = item[b];
    const int len = length[b];
    const int w = tid >> 6, l = tid & 63, lo16 = l & 15, hi = l >> 4;

    // ---- W2^T fragments in registers: w2f[nt][ks] ----
    bfrag w2f[3][3];
#pragma unroll
    for (int nt = 0; nt < 3; ++nt)
#pragma unroll
        for (int ks = 0; ks < 3; ++ks) {
            bfrag f;
#pragma unroll
            for (int i = 0; i < 8; ++i) {
                int k = ks * 32 + hi * 8 + i, j2 = nt * 16 + lo16;
                float v = (k < 80 && j2 < 40) ? W2[k * 40 + j2] : 0.f;
                f[i] = (short)f2b(v);
            }
            w2f[nt][ks] = f;
        }

    // ---- Phase A ----
    if (tid < 64)       sQ[tid] = item_table[(size_t)it * 64 + tid];
    else if (tid < 128) sQ[tid] = cate_table[(size_t)cate_list[it] * 64 + (tid - 64)];
    if (tid < TT) { int h = history[(size_t)b * TT + tid]; sHist[tid] = h; sCid[tid] = cate_list[h]; }
    if (tid < 48) { sB2[tid] = (tid < 40) ? b2[tid] : 0.f; sW3f[tid] = (tid < 40) ? W3[tid] : 0.f; }
    if (tid == 0) sB3v = b3[0];
    __syncthreads();

    // ---- Phase B: W1eff build (pairs), c-partials, stage pass-1 rows ----
    for (int i = tid; i < 5120; i += 512) {
        int j = i >> 6, kh = (i & 63) * 2;
        float4 p = *(const float4*)&W1pair[(size_t)(j * 128 + kh) * 2];
        float2 q = *(const float2*)&sQ[kh];
        unsigned pk = (unsigned)f2b(p.x + q.x * p.y) | ((unsigned)f2b(p.z + q.y * p.w) << 16);
        *(unsigned*)&sW1[j * 136 + kh] = pk;
    }
    if (tid < 480) {
        int g = tid / 80, j = tid - g * 80;
        int k0 = g * 22, k1e = (k0 + 22 < 128) ? k0 + 22 : 128;
        float c = 0.f;
        for (int k = k0; k < k1e; ++k) c = fmaf(sQ[k], W1ac[k * 80 + j], c);
        sCp[tid] = c;
    }
    if (tid < 448) {
        int r = tid >> 2, s = tid & 3;
        unsigned short* dst = &sA[r * 136 + s * 32];
        const float* src = (s < 2) ? (item_table + (size_t)sHist[r] * 64 + s * 32)
                                   : (cate_table + (size_t)sCid[r] * 64 + (s - 2) * 32);
#pragma unroll
        for (int q4 = 0; q4 < 8; ++q4) {
            float4 v = ((const float4*)src)[q4];
            ushort4 o; o.x = f2b(v.x); o.y = f2b(v.y); o.z = f2b(v.z); o.w = f2b(v.w);
            *(ushort4*)(dst + q4 * 4) = o;
        }
    }
    __syncthreads();

    // ---- Phase: sCc reduce; zero scores (clobbers sQ - dead) ----
    if (tid < 80) {
        float c = b1[tid];
#pragma unroll
        for (int g = 0; g < 6; ++g) c += sCp[g * 80 + tid];
        sCc[tid] = c;
    }
    if (tid < 256) sScore[tid] = 0.f;
    __syncthreads();

    // ---- layer1 pass1: 7 M x 5 N tiles ----
    f32x4 acc1[5];
#pragma unroll
    for (int pp = 0; pp < 5; ++pp) {
        int p = w + pp * 8;
        if (p < 35) {
            int mt = p / 5, nt = p - mt * 5;
            const unsigned short* Ab = &sA[(mt * 16 + lo16) * 136 + hi * 8];
            const unsigned short* Bb = &sW1[(nt * 16 + lo16) * 136 + hi * 8];
            f32x4 acc = {0.f, 0.f, 0.f, 0.f};
#pragma unroll
            for (int ks = 0; ks < 4; ++ks)
                acc = __builtin_amdgcn_mfma_f32_16x16x32_bf16(
                    *(const bfrag*)(Ab + ks * 32), *(const bfrag*)(Bb + ks * 32), acc, 0, 0, 0);
            acc1[pp] = acc;
        }
    }
    __syncthreads();   // sA reads done -> may restage

    // ---- sigmoid p1 -> sH1 ; zero k-pad cols ; stage pass-2 rows ----
#pragma unroll
    for (int pp = 0; pp < 5; ++pp) {
        int p = w + pp * 8;
        if (p < 35) {
            int mt = p / 5, nt = p - mt * 5;
            int j = nt * 16 + lo16;
            float cc = sCc[j];
#pragma unroll
            for (int rg = 0; rg < 4; ++rg)
                sH1[(mt * 16 + hi * 4 + rg) * 104 + j] = f2b(sigm(acc1[pp][rg] + cc));
        }
    }
    for (int i = tid; i < 112 * 16; i += 512) sH1[(i >> 4) * 104 + 80 + (i & 15)] = 0;
    if (tid < 448) {
        int r = tid >> 2, s = tid & 3;
        int t = 112 + r;
        unsigned short* dst = &sA[r * 136 + s * 32];
        if (t < TT) {
            const float* src = (s < 2) ? (item_table + (size_t)sHist[t] * 64 + s * 32)
                                       : (cate_table + (size_t)sCid[t] * 64 + (s - 2) * 32);
#pragma unroll
            for (int q4 = 0; q4 < 8; ++q4) {
                float4 v = ((const float4*)src)[q4];
                ushort4 o; o.x = f2b(v.x); o.y = f2b(v.y); o.z = f2b(v.z); o.w = f2b(v.w);
                *(ushort4*)(dst + q4 * 4) = o;
            }
        } else {
            ushort4 z = {0, 0, 0, 0};
#pragma unroll
            for (int q4 = 0; q4 < 8; ++q4) *(ushort4*)(dst + q4 * 4) = z;
        }
    }
    __syncthreads();

    // ---- layer1 pass2 MFMAs + layer2 pass1 (overlap) ----
    f32x4 acc2[5];
#pragma unroll
    for (int pp = 0; pp < 5; ++pp) {
        int p = w + pp * 8;
        if (p < 35) {
            int mt = p / 5, nt = p - mt * 5;
            const unsigned short* Ab = &sA[(mt * 16 + lo16) * 136 + hi * 8];
            const unsigned short* Bb = &sW1[(nt * 16 + lo16) * 136 + hi * 8];
            f32x4 acc = {0.f, 0.f, 0.f, 0.f};
#pragma unroll
            for (int ks = 0; ks < 4; ++ks)
                acc = __builtin_amdgcn_mfma_f32_16x16x32_bf16(
                    *(const bfrag*)(Ab + ks * 32), *(const bfrag*)(Bb + ks * 32), acc, 0, 0, 0);
            acc2[pp] = acc;
        }
    }
#pragma unroll
    for (int pp = 0; pp < 3; ++pp) {
        int p = w + pp * 8;
        if (p < 21) {
            int mt = p / 3, nt = p - mt * 3;
            const unsigned short* Ab = &sH1[(mt * 16 + lo16) * 104 + hi * 8];
            f32x4 acc = {0.f, 0.f, 0.f, 0.f};
#pragma unroll
            for (int ks = 0; ks < 3; ++ks)
                acc = __builtin_amdgcn_mfma_f32_16x16x32_bf16(
                    *(const bfrag*)(Ab + ks * 32), w2f[nt][ks], acc, 0, 0, 0);
            int j2 = nt * 16 + lo16;
            float w3 = sW3f[j2], b2v = sB2[j2];
#pragma unroll
            for (int rg = 0; rg < 4; ++rg) {
                float pt = sigm(acc[rg] + b2v) * w3;
                pt += __shfl_xor(pt, 1);
                pt += __shfl_xor(pt, 2);
                pt += __shfl_xor(pt, 4);
                pt += __shfl_xor(pt, 8);
                if (lo16 == 0) atomicAdd(&sScore[mt * 16 + hi * 4 + rg], pt);
            }
        }
    }
    __syncthreads();   // sH1 reads done

    // ---- sigmoid p2 -> sH1 (pads still zero) ----
#pragma unroll
    for (int pp = 0; pp < 5; ++pp) {
        int p = w + pp * 8;
        if (p < 35) {
            int mt = p / 5, nt = p - mt * 5;
            int j = nt * 16 + lo16;
            float cc = sCc[j];
#pragma unroll
            for (int rg = 0; rg < 4; ++rg)
                sH1[(mt * 16 + hi * 4 + rg) * 104 + j] = f2b(sigm(acc2[pp][rg] + cc));
        }
    }
    __syncthreads();

    // ---- layer2 pass2 ----
#pragma unroll
    for (int pp = 0; pp < 3; ++pp) {
        int p = w + pp * 8;
        if (p < 21) {
            int mt = p / 3, nt = p - mt * 3;
            const unsigned short* Ab = &sH1[(mt * 16 + lo16) * 104 + hi * 8];
            f32x4 acc = {0.f, 0.f, 0.f, 0.f};
#pragma unroll
            for (int ks = 0; ks < 3; ++ks)
                acc = __builtin_amdgcn_mfma_f32_16x16x32_bf16(
                    *(const bfrag*)(Ab + ks * 32), w2f[nt][ks], acc, 0, 0, 0);
            int j2 = nt * 16 + lo16;
            float w3 = sW3f[j2], b2v = sB2[j2];
#pragma unroll
            for (int rg = 0; rg < 4; ++rg) {
                float pt = sigm(acc[rg] + b2v) * w3;
                pt += __shfl_xor(pt, 1);
                pt += __shfl_xor(pt, 2);
                pt += __shfl_xor(pt, 4);
                pt += __shfl_xor(pt, 8);
                if (lo16 == 0) atomicAdd(&sScore[112 + mt * 16 + hi * 4 + rg], pt);
            }
        }
    }
    __syncthreads();

    // ---- softmax over T ----
    int t = tid;
    float sc;
    if (t < TT) {
        float raw = sScore[t] + sB3v;
        if (t >= len) raw = MASKV;
        sc = raw * INV_SQRTK;
    } else {
        sc = -3.0e38f;
    }
    float mx = sc;
#pragma unroll
    for (int o = 32; o > 0; o >>= 1) mx = fmaxf(mx, __shfl_xor(mx, o));
    if ((tid & 63) == 0) sRed[tid >> 6] = mx;
    __syncthreads();
    if (tid == 0) {
        float m2 = sRed[0];
        for (int ww = 1; ww < 8; ++ww) m2 = fmaxf(m2, sRed[ww]);
        sMS[0] = m2;
    }
    __syncthreads();
    mx = sMS[0];
    float e = (t < TT) ? __expf(sc - mx) : 0.f;
    float sum = e;
#pragma unroll
    for (int o = 32; o > 0; o >>= 1) sum += __shfl_xor(sum, o);
    if ((tid & 63) == 0) sRed[tid >> 6] = sum;
    __syncthreads();
    if (tid == 0) {
        float s2 = 0.f;
        for (int ww = 0; ww < 8; ++ww) s2 += sRed[ww];
        sMS[1] = s2;
    }
    __syncthreads();
    float inv = 1.f / sMS[1];
    if (t < TT) sScore[t] = e * inv;
    __syncthreads();

    // ---- Phase D: hist_attn = attn @ H (global gather, L3-resident) ----
    {
        const int rg = tid >> 5, c4 = tid & 31;
        f32x4 ad = {0.f, 0.f, 0.f, 0.f};
        for (int tt = rg; tt < TT; tt += 16) {
            float aw = sScore[tt];
            const float* p = (c4 < 16) ? (item_table + (size_t)sHist[tt] * 64 + c4 * 4)
                                       : (cate_table + (size_t)sCid[tt] * 64 + (c4 - 16) * 4);
            float4 v = *(const float4*)p;
            ad[0] = fmaf(aw, v.x, ad[0]);
            ad[1] = fmaf(aw, v.y, ad[1]);
            ad[2] = fmaf(aw, v.z, ad[2]);
            ad[3] = fmaf(aw, v.w, ad[3]);
        }
        *(f32x4*)&sPd[rg * 128 + c4 * 4] = ad;
    }
    __syncthreads();
    if (tid < 128) {
        float tot = 0.f;
#pragma unroll
        for (int g = 0; g < 16; ++g) tot += sPd[g * 128 + tid];
        hist_attn[(size_t)b * 128 + tid] = tot;
        atomicAdd(&hstats[tid], tot);
        atomicAdd(&hstats[128 + tid], tot * tot);
    }
}

// ---------------------------------------------------------------------------
// k_tail: fused K3..K6 via cooperative grid sync. 256 blocks x 256 threads.
// Block bid owns rows bid*8 .. bid*8+7 throughout; intermediates stay in LDS.
// ---------------------------------------------------------------------------
struct TailArgs {
    const float *hist_attn, *hstats;
    const float *hgamma, *hbeta, *histW, *histb;
    const int *user, *item, *cate_list;
    const float *user_table, *item_table, *cate_table;
    float *jstats, *p1stats, *p2stats;
    const float *fgamma, *fbeta, *fc1WT, *fc1b, *d1a, *d1b;
    const float *fc2WT, *fc2b, *d2a, *d2b, *fc3W, *fc3b, *item_bias;
    float *outp;
};

__global__ __launch_bounds__(256) void k_tail(TailArgs a)
{
    cg::grid_group grid = cg::this_grid();

    __shared__ float sWs[128 * 132];       // stage A: scaled histW ; stage B alias: sXn[8][388]
    __shared__ float sJoin[8 * 388];
    __shared__ float sX[8 * 132];          // stage A: hist_attn rows ; stage C alias: sX1[8][84]
    __shared__ float sScaleH[128], sShiftH[128], sCsP[2][128], sCb[128];
    __shared__ float sScaleJ[384], sShiftJ[384];
    __shared__ float sPre1[8 * 84];
    __shared__ float sPre2[8 * 44];
    __shared__ float sM1[80], sRs1[80], sA1[80], sBt1[80];
    __shared__ float sM2[40], sRs2[40], sA2[40], sBt2[40], sW3t[40];
    __shared__ float sB3t;

    float* const sXn = sWs;   // stage B
    float* const sX1 = sX;    // stage C

    const int tid = threadIdx.x;
    const int r0  = blockIdx.x * 8;

    // ================= Stage A: hist BN + hist_fc + join + jstats ==========
    if (tid < 128) {
        float m  = a.hstats[tid] * (1.f / 2048.f);
        float v  = a.hstats[128 + tid] * (1.f / 2048.f) - m * m;
        float rs = rsqrtf(v + BN_EPS);
        float scv = a.hgamma[tid] * rs;
        sScaleH[tid] = scv;
        sShiftH[tid] = a.hbeta[tid] - m * scv;
        sCb[tid] = a.histb[tid];
    }
    __syncthreads();
    for (int i = tid; i < 128 * 128; i += 256) {
        int k = i >> 7;
        sWs[k * 132 + (i & 127)] = sScaleH[k] * a.histW[i];
    }
    {
        int j = tid & 127, g = tid >> 7;
        float c = 0.f;
        for (int k = g * 64; k < g * 64 + 64; ++k) c = fmaf(sShiftH[k], a.histW[k * 128 + j], c);
        sCsP[g][j] = c;
    }
    for (int i = tid; i < 8 * 128; i += 256) {
        int r = i >> 7;
        sX[r * 132 + (i & 127)] = a.hist_attn[(size_t)(r0 + r) * 128 + (i & 127)];
    }
    __syncthreads();
    {
        const int j  = tid & 127;
        const int rh = tid >> 7;
        float su0 = 0.f, su1 = 0.f, su2 = 0.f, sq0 = 0.f, sq1 = 0.f, sq2 = 0.f;
        for (int r = rh; r < 8; r += 2) {
            int row = r0 + r;
            float o = sCsP[0][j] + sCsP[1][j] + sCb[j];
            for (int k = 0; k < 128; ++k) o = fmaf(sX[r * 132 + k], sWs[k * 132 + j], o);
            float ue = a.user_table[(size_t)a.user[row] * 128 + j];
            int itv  = a.item[row];
            float qv = (j < 64) ? a.item_table[(size_t)itv * 64 + j]
                                : a.cate_table[(size_t)a.cate_list[itv] * 64 + (j - 64)];
            sJoin[r * 388 + j]       = ue;
            sJoin[r * 388 + 128 + j] = qv;
            sJoin[r * 388 + 256 + j] = o;
            su0 += ue; sq0 = fmaf(ue, ue, sq0);
            su1 += qv; sq1 = fmaf(qv, qv, sq1);
            su2 += o;  sq2 = fmaf(o, o, sq2);
        }
        atomicAdd(&a.jstats[j], su0);       atomicAdd(&a.jstats[384 + j], sq0);
        atomicAdd(&a.jstats[128 + j], su1); atomicAdd(&a.jstats[384 + 128 + j], sq1);
        atomicAdd(&a.jstats[256 + j], su2); atomicAdd(&a.jstats[384 + 256 + j], sq2);
    }
    grid.sync();

    // ================= Stage B: BN(join) + fc1 + p1stats ===================
    for (int c = tid; c < 384; c += 256) {
        float m  = a.jstats[c] * (1.f / 2048.f);
        float v  = a.jstats[384 + c] * (1.f / 2048.f) - m * m;
        float rs = rsqrtf(v + BN_EPS);
        float scv = a.fgamma[c] * rs;
        sScaleJ[c] = scv;
        sShiftJ[c] = a.fbeta[c] - m * scv;
    }
    __syncthreads();
    for (int i = tid; i < 8 * 384; i += 256) {
        int r = i / 384, c = i - r * 384;
        sXn[r * 388 + c] = sJoin[r * 388 + c] * sScaleJ[c] + sShiftJ[c];
    }
    __syncthreads();
    {
        const int j1 = tid % 80;
        const int rg = tid / 80;
        if (rg < 3) {
            const float* wrow = a.fc1WT + (size_t)j1 * 384;
            float bias = a.fc1b[j1];
            float su = 0.f, sq = 0.f;
            for (int r = rg; r < 8; r += 3) {
                float acc = bias;
                for (int c = 0; c < 384; c += 4) {
                    float4 wv = *(const float4*)(wrow + c);
                    float4 xv = *(const float4*)&sXn[r * 388 + c];
                    acc = fmaf(wv.x, xv.x, fmaf(wv.y, xv.y, fmaf(wv.z, xv.z, fmaf(wv.w, xv.w, acc))));
                }
                sPre1[r * 84 + j1] = acc;
                su += acc;
                sq = fmaf(acc, acc, sq);
            }
            atomicAdd(&a.p1stats[j1], su);
            atomicAdd(&a.p1stats[80 + j1], sq);
        }
    }
    grid.sync();

    // ================= Stage C: dice1 + fc2 + p2stats ======================
    if (tid < 80) {
        float m = a.p1stats[tid] * (1.f / 2048.f);
        float v = a.p1stats[80 + tid] * (1.f / 2048.f) - m * m;
        sM1[tid]  = m;
        sRs1[tid] = rsqrtf(v + BN_EPS);
        sA1[tid]  = a.d1a[tid];
        sBt1[tid] = a.d1b[tid];
    }
    __syncthreads();
    for (int i = tid; i < 8 * 80; i += 256) {
        int r = i / 80, c = i - r * 80;
        float x  = sPre1[r * 84 + c];
        float xn = (x - sM1[c]) * sRs1[c];
        float p  = sigm(sBt1[c] * xn);
        sX1[r * 84 + c] = x * (p + sA1[c] * (1.f - p));
    }
    __syncthreads();
    {
        const int j2 = tid % 40;
        const int rg = tid / 40;
        if (rg < 6) {
            const float* wrow = a.fc2WT + (size_t)j2 * 80;
            float bias = a.fc2b[j2];
            float su = 0.f, sq = 0.f;
            for (int r = rg; r < 8; r += 6) {
                float acc = bias;
                for (int c = 0; c < 80; c += 4) {
                    float4 wv = *(const float4*)(wrow + c);
                    float4 xv = *(const float4*)&sX1[r * 84 + c];
                    acc = fmaf(wv.x, xv.x, fmaf(wv.y, xv.y, fmaf(wv.z, xv.z, fmaf(wv.w, xv.w, acc))));
                }
                sPre2[r * 44 + j2] = acc;
                su += acc;
                sq = fmaf(acc, acc, sq);
            }
            atomicAdd(&a.p2stats[j2], su);
            atomicAdd(&a.p2stats[40 + j2], sq);
        }
    }
    grid.sync();

    // ================= Stage D: dice2 + fc3 + bias + sigmoid ===============
    if (tid < 40) {
        float m = a.p2stats[tid] * (1.f / 2048.f);
        float v = a.p2stats[40 + tid] * (1.f / 2048.f) - m * m;
        sM2[tid]  = m;
        sRs2[tid] = rsqrtf(v + BN_EPS);
        sA2[tid]  = a.d2a[tid];
        sBt2[tid] = a.d2b[tid];
        sW3t[tid] = a.fc3W[tid];
    }
    if (tid == 0) sB3t = a.fc3b[0];
    __syncthreads();
    {
        const int r = tid >> 5, lane = tid & 31;
        float part = 0.f;
        int c = lane;
        {
            float x  = sPre2[r * 44 + c];
            float xn = (x - sM2[c]) * sRs2[c];
            float p  = sigm(sBt2[c] * xn);
            part = fmaf(x * (p + sA2[c] * (1.f - p)), sW3t[c], part);
        }
        if (lane < 8) {
            int c2 = lane + 32;
            float x  = sPre2[r * 44 + c2];
            float xn = (x - sM2[c2]) * sRs2[c2];
            float p  = sigm(sBt2[c2] * xn);
            part = fmaf(x * (p + sA2[c2] * (1.f - p)), sW3t[c2], part);
        }
#pragma unroll
        for (int o = 16; o > 0; o >>= 1) part += __shfl_xor(part, o);
        if (lane == 0) {
            int row = r0 + r;
            float v = part + sB3t + a.item_bias[a.item[row]];
            a.outp[row]      = v;
            a.outp[BB + row] = sigm(v);
        }
    }
}

// ---------------------------------------------------------------------------
extern "C" void kernel_launch(void* const* d_in, const int* in_sizes, int n_in,
                              void* d_out, int out_size, void* d_ws, size_t ws_size,
                              hipStream_t stream)
{
    const int*   user       = (const int*)d_in[0];
    const int*   item       = (const int*)d_in[1];
    const int*   history    = (const int*)d_in[2];
    const int*   length     = (const int*)d_in[3];
    const int*   cate_list  = (const int*)d_in[4];
    const float* user_table = (const float*)d_in[5];
    const float* item_table = (const float*)d_in[6];
    const float* cate_table = (const float*)d_in[7];
    const float* item_bias  = (const float*)d_in[8];
    const float* att_W1 = (const float*)d_in[9];
    const float* att_b1 = (const float*)d_in[10];
    const float* att_W2 = (const float*)d_in[11];
    const float* att_b2 = (const float*)d_in[12];
    const float* att_W3 = (const float*)d_in[13];
    const float* att_b3 = (const float*)d_in[14];
    const float* hgam   = (const float*)d_in[15];
    const float* hbet   = (const float*)d_in[16];
    const float* histW  = (const float*)d_in[17];
    const float* histb  = (const float*)d_in[18];
    const float* fgam   = (const float*)d_in[19];
    const float* fbet   = (const float*)d_in[20];
    const float* fc1W   = (const float*)d_in[21];
    const float* fc1b   = (const float*)d_in[22];
    const float* d1a    = (const float*)d_in[23];
    const float* d1b    = (const float*)d_in[24];
    const float* fc2W   = (const float*)d_in[25];
    const float* fc2b   = (const float*)d_in[26];
    const float* d2a    = (const float*)d_in[27];
    const float* d2b    = (const float*)d_in[28];
    const float* fc3W   = (const float*)d_in[29];
    const float* fc3b   = (const float*)d_in[30];

    float* ws        = (float*)d_ws;
    float* hist_attn = ws;                    // 262144
    float* stats     = hist_attn + 262144;    // 1264
    float* hstats  = stats;                   // 256
    float* jstats  = stats + 256;             // 768
    float* p1stats = jstats + 768;            // 160
    float* p2stats = p1stats + 160;           // 80
    float* prep    = stats + 1264;            // 64640
    float* W1pair = prep;
    float* W1ac   = prep + 20480;
    float* fc1WT  = prep + 30720;
    float* fc2WT  = prep + 61440;

    hipMemsetAsync(stats, 0, 1264 * sizeof(float), stream);

    k0_prep<<<128, 256, 0, stream>>>(att_W1, fc1W, fc2W, prep);

    k1_attn<<<BB, 512, 0, stream>>>(item, history, length, cate_list,
        item_table, cate_table, W1pair, W1ac,
        att_b1, att_W2, att_b2, att_W3, att_b3,
        hist_attn, hstats);

    TailArgs ta;
    ta.hist_attn = hist_attn; ta.hstats = hstats;
    ta.hgamma = hgam; ta.hbeta = hbet; ta.histW = histW; ta.histb = histb;
    ta.user = user; ta.item = item; ta.cate_list = cate_list;
    ta.user_table = user_table; ta.item_table = item_table; ta.cate_table = cate_table;
    ta.jstats = jstats; ta.p1stats = p1stats; ta.p2stats = p2stats;
    ta.fgamma = fgam; ta.fbeta = fbet; ta.fc1WT = fc1WT; ta.fc1b = fc1b;
    ta.d1a = d1a; ta.d1b = d1b; ta.fc2WT = fc2WT; ta.fc2b = fc2b;
    ta.d2a = d2a; ta.d2b = d2b; ta.fc3W = fc3W; ta.fc3b = fc3b;
    ta.item_bias = item_bias; ta.outp = (float*)d_out;

    void* kargs[] = { &ta };
    hipLaunchCooperativeKernel((void*)k_tail, dim3(256), dim3(256), kargs, 0, stream);
}

// Round 4
// 508.291 us; speedup vs baseline: 1.1047x; 1.1047x over previous
//
#include <hip/hip_runtime.h>
#include <math.h>

#define BB 2048
#define TT 200
#define BN_EPS 1e-3f
#define MASKV (-4294967295.0f)
#define INV_SQRTK 0.08838834764831845f

typedef short bfrag __attribute__((ext_vector_type(8)));
typedef float f32x4 __attribute__((ext_vector_type(4)));

__device__ __forceinline__ unsigned short f2b(float x) {
    union { float f; unsigned u; } v; v.f = x;
    unsigned r = (v.u + 0x7fffu + ((v.u >> 16) & 1u)) >> 16;
    return (unsigned short)r;
}
__device__ __forceinline__ float b2f(unsigned short u) {
    union { unsigned u; float f; } v; v.u = ((unsigned)u) << 16; return v.f;
}
__device__ __forceinline__ float sigm(float x) { return 1.f / (1.f + __expf(-x)); }

// ---------------------------------------------------------------------------
// k0: weight prep (block-invariant).
// ---------------------------------------------------------------------------
__global__ __launch_bounds__(256) void k0_prep(
    const float* __restrict__ W1, const float* __restrict__ fc1W,
    const float* __restrict__ fc2W, float* __restrict__ prep)
{
    const int gid = blockIdx.x * 256 + threadIdx.x;
    const int stride = gridDim.x * 256;
    float* W1pair = prep;                 // 20480
    float* W1ac   = prep + 20480;         // 10240
    float* fc1WT  = prep + 30720;         // 30720
    float* fc2WT  = prep + 61440;         // 3200
    for (int i = gid; i < 10240; i += stride) {
        int j = i >> 7, k = i & 127;
        float wa = W1[k * 80 + j];
        float wb = W1[(128 + k) * 80 + j];
        float wc = W1[(256 + k) * 80 + j];
        float wd = W1[(384 + k) * 80 + j];
        W1pair[i * 2]     = wb - wc;
        W1pair[i * 2 + 1] = wd;
        W1ac[k * 80 + j]  = wa + wc;
    }
    for (int i = gid; i < 30720; i += stride) { int j = i / 384, c = i - j * 384; fc1WT[i] = fc1W[c * 80 + j]; }
    for (int i = gid; i < 3200;  i += stride) { int j = i / 80,  c = i - j * 80;  fc2WT[i] = fc2W[c * 40 + j]; }
}

// ---------------------------------------------------------------------------
// K1: DIN attention. 2048 blocks x 512 thr, ~79KB LDS -> 2 blocks/CU.
// Layer-2 uses STATIC wave decomposition (no runtime-indexed reg arrays).
// Phase D reads hist rows from LDS bf16 (two halves), no global re-gather.
// ---------------------------------------------------------------------------
__global__ __launch_bounds__(512, 4) void k1_attn(
    const int* __restrict__ item, const int* __restrict__ history,
    const int* __restrict__ length, const int* __restrict__ cate_list,
    const float* __restrict__ item_table, const float* __restrict__ cate_table,
    const float* __restrict__ W1pair, const float* __restrict__ W1ac,
    const float* __restrict__ b1, const float* __restrict__ W2,
    const float* __restrict__ b2, const float* __restrict__ W3,
    const float* __restrict__ b3,
    float* __restrict__ hist_attn, float* __restrict__ hstats)
{
    __shared__ __align__(16) unsigned short sA[112 * 136];   // 30464 B
    __shared__ __align__(16) unsigned short sW1[80 * 136];   // 21760 B
    __shared__ __align__(16) unsigned short sH1[112 * 104];  // 23296 B (alias: sCp, sPd)
    __shared__ float sScore[256];                            // alias: sQ
    __shared__ float sCc[80];
    __shared__ int   sHist[TT], sCid[TT];
    __shared__ float sB2[48], sW3f[48];
    __shared__ float sRed[8], sMS[2], sB3v;

    float* const sQ  = sScore;        // 128 floats, dead before sScore zeroed
    float* const sCp = (float*)sH1;   // 480 floats, phase B only
    float* const sPd = (float*)sH1;   // 8*128 floats, phase D only

    const int b   = blockIdx.x;
    const int tid = threadIdx.x;
    const int it  = item[b];
    const int len = length[b];
    const int w = tid >> 6, l = tid & 63, lo16 = l & 15, hi = l >> 4;

    // ---- W2^T fragments in registers (all indices compile-time) ----
    bfrag w2f[3][3];
#pragma unroll
    for (int nt = 0; nt < 3; ++nt)
#pragma unroll
        for (int ks = 0; ks < 3; ++ks) {
            bfrag f;
#pragma unroll
            for (int i = 0; i < 8; ++i) {
                int k = ks * 32 + hi * 8 + i, j2 = nt * 16 + lo16;
                float v = (k < 80 && j2 < 40) ? W2[k * 40 + j2] : 0.f;
                f[i] = (short)f2b(v);
            }
            w2f[nt][ks] = f;
        }

    // ---- Phase A ----
    if (tid < 64)       sQ[tid] = item_table[(size_t)it * 64 + tid];
    else if (tid < 128) sQ[tid] = cate_table[(size_t)cate_list[it] * 64 + (tid - 64)];
    if (tid < TT) { int h = history[(size_t)b * TT + tid]; sHist[tid] = h; sCid[tid] = cate_list[h]; }
    if (tid < 48) { sB2[tid] = (tid < 40) ? b2[tid] : 0.f; sW3f[tid] = (tid < 40) ? W3[tid] : 0.f; }
    if (tid == 0) sB3v = b3[0];
    __syncthreads();

    // ---- Phase B: W1eff build, c-partials, stage rows 0..111 ----
    for (int i = tid; i < 5120; i += 512) {
        int j = i >> 6, kh = (i & 63) * 2;
        float4 p = *(const float4*)&W1pair[(size_t)(j * 128 + kh) * 2];
        float2 q = *(const float2*)&sQ[kh];
        unsigned pk = (unsigned)f2b(p.x + q.x * p.y) | ((unsigned)f2b(p.z + q.y * p.w) << 16);
        *(unsigned*)&sW1[j * 136 + kh] = pk;
    }
    if (tid < 480) {
        int g = tid / 80, j = tid - g * 80;
        int k0 = g * 22, k1e = (k0 + 22 < 128) ? k0 + 22 : 128;
        float c = 0.f;
        for (int k = k0; k < k1e; ++k) c = fmaf(sQ[k], W1ac[k * 80 + j], c);
        sCp[tid] = c;
    }
    if (tid < 448) {
        int r = tid >> 2, s = tid & 3;
        unsigned short* dst = &sA[r * 136 + s * 32];
        const float* src = (s < 2) ? (item_table + (size_t)sHist[r] * 64 + s * 32)
                                   : (cate_table + (size_t)sCid[r] * 64 + (s - 2) * 32);
#pragma unroll
        for (int q4 = 0; q4 < 8; ++q4) {
            float4 v = ((const float4*)src)[q4];
            ushort4 o; o.x = f2b(v.x); o.y = f2b(v.y); o.z = f2b(v.z); o.w = f2b(v.w);
            *(ushort4*)(dst + q4 * 4) = o;
        }
    }
    __syncthreads();

    // ---- Phase C: sCc reduce ; zero scores (clobbers dead sQ) ----
    if (tid < 80) {
        float c = b1[tid];
#pragma unroll
        for (int g = 0; g < 6; ++g) c += sCp[g * 80 + tid];
        sCc[tid] = c;
    }
    if (tid < 256) sScore[tid] = 0.f;
    __syncthreads();

    // ---- layer1 pass1: 7 Mt x 5 Nt ----
    f32x4 acc1[5];
#pragma unroll
    for (int pp = 0; pp < 5; ++pp) {
        int p = w + pp * 8;
        if (p < 35) {
            int mt = p / 5, nt = p - mt * 5;
            const unsigned short* Ab = &sA[(mt * 16 + lo16) * 136 + hi * 8];
            const unsigned short* Bb = &sW1[(nt * 16 + lo16) * 136 + hi * 8];
            f32x4 acc = {0.f, 0.f, 0.f, 0.f};
#pragma unroll
            for (int ks = 0; ks < 4; ++ks)
                acc = __builtin_amdgcn_mfma_f32_16x16x32_bf16(
                    *(const bfrag*)(Ab + ks * 32), *(const bfrag*)(Bb + ks * 32), acc, 0, 0, 0);
            acc1[pp] = acc;
        }
    }
    __syncthreads();   // sA reads done -> restage; sCp dead -> sH1

    // ---- sigmoid p1 -> sH1 ; zero k-pads ; stage rows 112..207 ----
#pragma unroll
    for (int pp = 0; pp < 5; ++pp) {
        int p = w + pp * 8;
        if (p < 35) {
            int mt = p / 5, nt = p - mt * 5;
            int j = nt * 16 + lo16;
            float cc = sCc[j];
#pragma unroll
            for (int rg = 0; rg < 4; ++rg)
                sH1[(mt * 16 + hi * 4 + rg) * 104 + j] = f2b(sigm(acc1[pp][rg] + cc));
        }
    }
    for (int i = tid; i < 112 * 16; i += 512) sH1[(i >> 4) * 104 + 80 + (i & 15)] = 0;
    if (tid < 448) {
        int r = tid >> 2, s = tid & 3;
        int t = 112 + r;
        unsigned short* dst = &sA[r * 136 + s * 32];
        if (t < TT) {
            const float* src = (s < 2) ? (item_table + (size_t)sHist[t] * 64 + s * 32)
                                       : (cate_table + (size_t)sCid[t] * 64 + (s - 2) * 32);
#pragma unroll
            for (int q4 = 0; q4 < 8; ++q4) {
                float4 v = ((const float4*)src)[q4];
                ushort4 o; o.x = f2b(v.x); o.y = f2b(v.y); o.z = f2b(v.z); o.w = f2b(v.w);
                *(ushort4*)(dst + q4 * 4) = o;
            }
        } else {
            ushort4 z = {0, 0, 0, 0};
#pragma unroll
            for (int q4 = 0; q4 < 8; ++q4) *(ushort4*)(dst + q4 * 4) = z;
        }
    }
    __syncthreads();

    // ---- layer1 pass2 + layer2 pass1 (static: wave w<7 owns mt=w) ----
    f32x4 acc2[5];
#pragma unroll
    for (int pp = 0; pp < 5; ++pp) {
        int p = w + pp * 8;
        if (p < 35) {
            int mt = p / 5, nt = p - mt * 5;
            const unsigned short* Ab = &sA[(mt * 16 + lo16) * 136 + hi * 8];
            const unsigned short* Bb = &sW1[(nt * 16 + lo16) * 136 + hi * 8];
            f32x4 acc = {0.f, 0.f, 0.f, 0.f};
#pragma unroll
            for (int ks = 0; ks < 4; ++ks)
                acc = __builtin_amdgcn_mfma_f32_16x16x32_bf16(
                    *(const bfrag*)(Ab + ks * 32), *(const bfrag*)(Bb + ks * 32), acc, 0, 0, 0);
            acc2[pp] = acc;
        }
    }
    if (w < 7) {
        bfrag af[3];
        const unsigned short* Ab = &sH1[(w * 16 + lo16) * 104 + hi * 8];
#pragma unroll
        for (int ks = 0; ks < 3; ++ks) af[ks] = *(const bfrag*)(Ab + ks * 32);
        f32x4 accl2[3];
#pragma unroll
        for (int nt = 0; nt < 3; ++nt) {
            f32x4 acc = {0.f, 0.f, 0.f, 0.f};
#pragma unroll
            for (int ks = 0; ks < 3; ++ks)
                acc = __builtin_amdgcn_mfma_f32_16x16x32_bf16(af[ks], w2f[nt][ks], acc, 0, 0, 0);
            accl2[nt] = acc;
        }
#pragma unroll
        for (int nt = 0; nt < 3; ++nt) {
            int j2 = nt * 16 + lo16;
            float w3 = sW3f[j2], b2v = sB2[j2];
#pragma unroll
            for (int rg = 0; rg < 4; ++rg) {
                float pt = sigm(accl2[nt][rg] + b2v) * w3;
                pt += __shfl_xor(pt, 1);
                pt += __shfl_xor(pt, 2);
                pt += __shfl_xor(pt, 4);
                pt += __shfl_xor(pt, 8);
                if (lo16 == 0) atomicAdd(&sScore[w * 16 + hi * 4 + rg], pt);
            }
        }
    }
    __syncthreads();   // sH1 reads done

    // ---- sigmoid p2 -> sH1 (pads persist) ----
#pragma unroll
    for (int pp = 0; pp < 5; ++pp) {
        int p = w + pp * 8;
        if (p < 35) {
            int mt = p / 5, nt = p - mt * 5;
            int j = nt * 16 + lo16;
            float cc = sCc[j];
#pragma unroll
            for (int rg = 0; rg < 4; ++rg)
                sH1[(mt * 16 + hi * 4 + rg) * 104 + j] = f2b(sigm(acc2[pp][rg] + cc));
        }
    }
    __syncthreads();

    // ---- layer2 pass2 (static) ----
    if (w < 7) {
        bfrag af[3];
        const unsigned short* Ab = &sH1[(w * 16 + lo16) * 104 + hi * 8];
#pragma unroll
        for (int ks = 0; ks < 3; ++ks) af[ks] = *(const bfrag*)(Ab + ks * 32);
        f32x4 accl2[3];
#pragma unroll
        for (int nt = 0; nt < 3; ++nt) {
            f32x4 acc = {0.f, 0.f, 0.f, 0.f};
#pragma unroll
            for (int ks = 0; ks < 3; ++ks)
                acc = __builtin_amdgcn_mfma_f32_16x16x32_bf16(af[ks], w2f[nt][ks], acc, 0, 0, 0);
            accl2[nt] = acc;
        }
#pragma unroll
        for (int nt = 0; nt < 3; ++nt) {
            int j2 = nt * 16 + lo16;
            float w3 = sW3f[j2], b2v = sB2[j2];
#pragma unroll
            for (int rg = 0; rg < 4; ++rg) {
                float pt = sigm(accl2[nt][rg] + b2v) * w3;
                pt += __shfl_xor(pt, 1);
                pt += __shfl_xor(pt, 2);
                pt += __shfl_xor(pt, 4);
                pt += __shfl_xor(pt, 8);
                if (lo16 == 0) atomicAdd(&sScore[112 + w * 16 + hi * 4 + rg], pt);
            }
        }
    }
    __syncthreads();

    // ---- softmax over T ----
    int t = tid;
    float sc;
    if (t < TT) {
        float raw = sScore[t] + sB3v;
        if (t >= len) raw = MASKV;
        sc = raw * INV_SQRTK;
    } else {
        sc = -3.0e38f;
    }
    float mx = sc;
#pragma unroll
    for (int o = 32; o > 0; o >>= 1) mx = fmaxf(mx, __shfl_xor(mx, o));
    if ((tid & 63) == 0) sRed[tid >> 6] = mx;
    __syncthreads();
    if (tid == 0) {
        float m2 = sRed[0];
        for (int ww = 1; ww < 8; ++ww) m2 = fmaxf(m2, sRed[ww]);
        sMS[0] = m2;
    }
    __syncthreads();
    mx = sMS[0];
    float e = (t < TT) ? __expf(sc - mx) : 0.f;
    float sum = e;
#pragma unroll
    for (int o = 32; o > 0; o >>= 1) sum += __shfl_xor(sum, o);
    if ((tid & 63) == 0) sRed[tid >> 6] = sum;
    __syncthreads();
    if (tid == 0) {
        float s2 = 0.f;
        for (int ww = 0; ww < 8; ++ww) s2 += sRed[ww];
        sMS[1] = s2;
    }
    __syncthreads();
    float inv = 1.f / sMS[1];
    if (t < TT) sScore[t] = e * inv;
    __syncthreads();

    // ---- Phase D: attn @ H from LDS bf16, two halves ----
    const int k2 = l * 2;     // column pair 0..126
    const int g  = tid >> 6;  // 0..7
    float a0 = 0.f, a1 = 0.f;
    // half A: rows 112..199 are resident in sA (row = t-112)
    for (int tt = 112 + g; tt < TT; tt += 8) {
        float aw = sScore[tt];
        unsigned pr = *(const unsigned*)&sA[(tt - 112) * 136 + k2];
        a0 = fmaf(aw, b2f((unsigned short)(pr & 0xffffu)), a0);
        a1 = fmaf(aw, b2f((unsigned short)(pr >> 16)), a1);
    }
    __syncthreads();
    // restage rows 0..111
    if (tid < 448) {
        int r = tid >> 2, s = tid & 3;
        unsigned short* dst = &sA[r * 136 + s * 32];
        const float* src = (s < 2) ? (item_table + (size_t)sHist[r] * 64 + s * 32)
                                   : (cate_table + (size_t)sCid[r] * 64 + (s - 2) * 32);
#pragma unroll
        for (int q4 = 0; q4 < 8; ++q4) {
            float4 v = ((const float4*)src)[q4];
            ushort4 o; o.x = f2b(v.x); o.y = f2b(v.y); o.z = f2b(v.z); o.w = f2b(v.w);
            *(ushort4*)(dst + q4 * 4) = o;
        }
    }
    __syncthreads();
    for (int tt = g; tt < 112; tt += 8) {
        float aw = sScore[tt];
        unsigned pr = *(const unsigned*)&sA[tt * 136 + k2];
        a0 = fmaf(aw, b2f((unsigned short)(pr & 0xffffu)), a0);
        a1 = fmaf(aw, b2f((unsigned short)(pr >> 16)), a1);
    }
    __syncthreads();   // sH1 (sPd alias) fully dead
    sPd[g * 128 + k2]     = a0;
    sPd[g * 128 + k2 + 1] = a1;
    __syncthreads();
    if (tid < 128) {
        float tot = 0.f;
#pragma unroll
        for (int gg = 0; gg < 8; ++gg) tot += sPd[gg * 128 + tid];
        hist_attn[(size_t)b * 128 + tid] = tot;
        atomicAdd(&hstats[tid], tot);
        atomicAdd(&hstats[128 + tid], tot * tot);
    }
}

// ---------------------------------------------------------------------------
// k_tail: fused K3..K6, regular launch, manual grid barrier.
// 256 blocks x 256 threads, 1 block/CU (grid == CU count) -> all resident.
// ---------------------------------------------------------------------------
struct TailArgs {
    const float *hist_attn, *hstats;
    const float *hgamma, *hbeta, *histW, *histb;
    const int *user, *item, *cate_list;
    const float *user_table, *item_table, *cate_table;
    float *jstats, *p1stats, *p2stats;
    const float *fgamma, *fbeta, *fc1WT, *fc1b, *d1a, *d1b;
    const float *fc2WT, *fc2b, *d2a, *d2b, *fc3W, *fc3b, *item_bias;
    float *outp;
    int *bar;   // [counter, gen], zeroed each launch
};

__device__ __forceinline__ void grid_barrier(int* bar, int nblocks) {
    __syncthreads();
    if (threadIdx.x == 0) {
        int* counter = bar;
        int* gen     = bar + 1;
        int g = __hip_atomic_load(gen, __ATOMIC_ACQUIRE, __HIP_MEMORY_SCOPE_AGENT);
        __threadfence();
        int t = __hip_atomic_fetch_add(counter, 1, __ATOMIC_ACQ_REL, __HIP_MEMORY_SCOPE_AGENT);
        if (t == nblocks - 1) {
            __hip_atomic_store(counter, 0, __ATOMIC_RELEASE, __HIP_MEMORY_SCOPE_AGENT);
            __hip_atomic_fetch_add(gen, 1, __ATOMIC_ACQ_REL, __HIP_MEMORY_SCOPE_AGENT);
        } else {
            while (__hip_atomic_load(gen, __ATOMIC_ACQUIRE, __HIP_MEMORY_SCOPE_AGENT) == g) {}
        }
        __threadfence();
    }
    __syncthreads();
}

__global__ __launch_bounds__(256) void k_tail(TailArgs a)
{
    __shared__ float sWs[128 * 132];       // stage A ; stage B alias: sXn[8][388]
    __shared__ float sJoin[8 * 388];
    __shared__ float sX[8 * 132];          // stage A ; stage C alias: sX1[8][84]
    __shared__ float sScaleH[128], sShiftH[128], sCsP[2][128], sCb[128];
    __shared__ float sScaleJ[384], sShiftJ[384];
    __shared__ float sPre1[8 * 84];
    __shared__ float sPre2[8 * 44];
    __shared__ float sM1[80], sRs1[80], sA1[80], sBt1[80];
    __shared__ float sM2[40], sRs2[40], sA2[40], sBt2[40], sW3t[40];
    __shared__ float sB3t;

    float* const sXn = sWs;
    float* const sX1 = sX;

    const int tid = threadIdx.x;
    const int r0  = blockIdx.x * 8;
    const int NB  = 256;

    // ================= Stage A: hist BN + hist_fc + join + jstats ==========
    if (tid < 128) {
        float m  = a.hstats[tid] * (1.f / 2048.f);
        float v  = a.hstats[128 + tid] * (1.f / 2048.f) - m * m;
        float rs = rsqrtf(v + BN_EPS);
        float scv = a.hgamma[tid] * rs;
        sScaleH[tid] = scv;
        sShiftH[tid] = a.hbeta[tid] - m * scv;
        sCb[tid] = a.histb[tid];
    }
    __syncthreads();
    for (int i = tid; i < 128 * 128; i += 256) {
        int k = i >> 7;
        sWs[k * 132 + (i & 127)] = sScaleH[k] * a.histW[i];
    }
    {
        int j = tid & 127, g = tid >> 7;
        float c = 0.f;
        for (int k = g * 64; k < g * 64 + 64; ++k) c = fmaf(sShiftH[k], a.histW[k * 128 + j], c);
        sCsP[g][j] = c;
    }
    for (int i = tid; i < 8 * 128; i += 256) {
        int r = i >> 7;
        sX[r * 132 + (i & 127)] = a.hist_attn[(size_t)(r0 + r) * 128 + (i & 127)];
    }
    __syncthreads();
    {
        const int j  = tid & 127;
        const int rh = tid >> 7;
        float su0 = 0.f, su1 = 0.f, su2 = 0.f, sq0 = 0.f, sq1 = 0.f, sq2 = 0.f;
        for (int r = rh; r < 8; r += 2) {
            int row = r0 + r;
            float o = sCsP[0][j] + sCsP[1][j] + sCb[j];
            for (int k = 0; k < 128; ++k) o = fmaf(sX[r * 132 + k], sWs[k * 132 + j], o);
            float ue = a.user_table[(size_t)a.user[row] * 128 + j];
            int itv  = a.item[row];
            float qv = (j < 64) ? a.item_table[(size_t)itv * 64 + j]
                                : a.cate_table[(size_t)a.cate_list[itv] * 64 + (j - 64)];
            sJoin[r * 388 + j]       = ue;
            sJoin[r * 388 + 128 + j] = qv;
            sJoin[r * 388 + 256 + j] = o;
            su0 += ue; sq0 = fmaf(ue, ue, sq0);
            su1 += qv; sq1 = fmaf(qv, qv, sq1);
            su2 += o;  sq2 = fmaf(o, o, sq2);
        }
        atomicAdd(&a.jstats[j], su0);       atomicAdd(&a.jstats[384 + j], sq0);
        atomicAdd(&a.jstats[128 + j], su1); atomicAdd(&a.jstats[384 + 128 + j], sq1);
        atomicAdd(&a.jstats[256 + j], su2); atomicAdd(&a.jstats[384 + 256 + j], sq2);
    }
    grid_barrier(a.bar, NB);

    // ================= Stage B: BN(join) + fc1 + p1stats ===================
    for (int c = tid; c < 384; c += 256) {
        float m  = a.jstats[c] * (1.f / 2048.f);
        float v  = a.jstats[384 + c] * (1.f / 2048.f) - m * m;
        float rs = rsqrtf(v + BN_EPS);
        float scv = a.fgamma[c] * rs;
        sScaleJ[c] = scv;
        sShiftJ[c] = a.fbeta[c] - m * scv;
    }
    __syncthreads();
    for (int i = tid; i < 8 * 384; i += 256) {
        int r = i / 384, c = i - r * 384;
        sXn[r * 388 + c] = sJoin[r * 388 + c] * sScaleJ[c] + sShiftJ[c];
    }
    __syncthreads();
    {
        const int j1 = tid % 80;
        const int rg = tid / 80;
        if (rg < 3) {
            const float* wrow = a.fc1WT + (size_t)j1 * 384;
            float bias = a.fc1b[j1];
            float su = 0.f, sq = 0.f;
            for (int r = rg; r < 8; r += 3) {
                float acc = bias;
                for (int c = 0; c < 384; c += 4) {
                    float4 wv = *(const float4*)(wrow + c);
                    float4 xv = *(const float4*)&sXn[r * 388 + c];
                    acc = fmaf(wv.x, xv.x, fmaf(wv.y, xv.y, fmaf(wv.z, xv.z, fmaf(wv.w, xv.w, acc))));
                }
                sPre1[r * 84 + j1] = acc;
                su += acc;
                sq = fmaf(acc, acc, sq);
            }
            atomicAdd(&a.p1stats[j1], su);
            atomicAdd(&a.p1stats[80 + j1], sq);
        }
    }
    grid_barrier(a.bar, NB);

    // ================= Stage C: dice1 + fc2 + p2stats ======================
    if (tid < 80) {
        float m = a.p1stats[tid] * (1.f / 2048.f);
        float v = a.p1stats[80 + tid] * (1.f / 2048.f) - m * m;
        sM1[tid]  = m;
        sRs1[tid] = rsqrtf(v + BN_EPS);
        sA1[tid]  = a.d1a[tid];
        sBt1[tid] = a.d1b[tid];
    }
    __syncthreads();
    for (int i = tid; i < 8 * 80; i += 256) {
        int r = i / 80, c = i - r * 80;
        float x  = sPre1[r * 84 + c];
        float xn = (x - sM1[c]) * sRs1[c];
        float p  = sigm(sBt1[c] * xn);
        sX1[r * 84 + c] = x * (p + sA1[c] * (1.f - p));
    }
    __syncthreads();
    {
        const int j2 = tid % 40;
        const int rg = tid / 40;
        if (rg < 6) {
            const float* wrow = a.fc2WT + (size_t)j2 * 80;
            float bias = a.fc2b[j2];
            float su = 0.f, sq = 0.f;
            for (int r = rg; r < 8; r += 6) {
                float acc = bias;
                for (int c = 0; c < 80; c += 4) {
                    float4 wv = *(const float4*)(wrow + c);
                    float4 xv = *(const float4*)&sX1[r * 84 + c];
                    acc = fmaf(wv.x, xv.x, fmaf(wv.y, xv.y, fmaf(wv.z, xv.z, fmaf(wv.w, xv.w, acc))));
                }
                sPre2[r * 44 + j2] = acc;
                su += acc;
                sq = fmaf(acc, acc, sq);
            }
            atomicAdd(&a.p2stats[j2], su);
            atomicAdd(&a.p2stats[40 + j2], sq);
        }
    }
    grid_barrier(a.bar, NB);

    // ================= Stage D: dice2 + fc3 + bias + sigmoid ===============
    if (tid < 40) {
        float m = a.p2stats[tid] * (1.f / 2048.f);
        float v = a.p2stats[40 + tid] * (1.f / 2048.f) - m * m;
        sM2[tid]  = m;
        sRs2[tid] = rsqrtf(v + BN_EPS);
        sA2[tid]  = a.d2a[tid];
        sBt2[tid] = a.d2b[tid];
        sW3t[tid] = a.fc3W[tid];
    }
    if (tid == 0) sB3t = a.fc3b[0];
    __syncthreads();
    {
        const int r = tid >> 5, lane = tid & 31;
        float part = 0.f;
        {
            int c = lane;
            float x  = sPre2[r * 44 + c];
            float xn = (x - sM2[c]) * sRs2[c];
            float p  = sigm(sBt2[c] * xn);
            part = fmaf(x * (p + sA2[c] * (1.f - p)), sW3t[c], part);
        }
        if (lane < 8) {
            int c2 = lane + 32;
            float x  = sPre2[r * 44 + c2];
            float xn = (x - sM2[c2]) * sRs2[c2];
            float p  = sigm(sBt2[c2] * xn);
            part = fmaf(x * (p + sA2[c2] * (1.f - p)), sW3t[c2], part);
        }
#pragma unroll
        for (int o = 16; o > 0; o >>= 1) part += __shfl_xor(part, o);
        if (lane == 0) {
            int row = r0 + r;
            float v = part + sB3t + a.item_bias[a.item[row]];
            a.outp[row]      = v;
            a.outp[BB + row] = sigm(v);
        }
    }
}

// ---------------------------------------------------------------------------
extern "C" void kernel_launch(void* const* d_in, const int* in_sizes, int n_in,
                              void* d_out, int out_size, void* d_ws, size_t ws_size,
                              hipStream_t stream)
{
    const int*   user       = (const int*)d_in[0];
    const int*   item       = (const int*)d_in[1];
    const int*   history    = (const int*)d_in[2];
    const int*   length     = (const int*)d_in[3];
    const int*   cate_list  = (const int*)d_in[4];
    const float* user_table = (const float*)d_in[5];
    const float* item_table = (const float*)d_in[6];
    const float* cate_table = (const float*)d_in[7];
    const float* item_bias  = (const float*)d_in[8];
    const float* att_W1 = (const float*)d_in[9];
    const float* att_b1 = (const float*)d_in[10];
    const float* att_W2 = (const float*)d_in[11];
    const float* att_b2 = (const float*)d_in[12];
    const float* att_W3 = (const float*)d_in[13];
    const float* att_b3 = (const float*)d_in[14];
    const float* hgam   = (const float*)d_in[15];
    const float* hbet   = (const float*)d_in[16];
    const float* histW  = (const float*)d_in[17];
    const float* histb  = (const float*)d_in[18];
    const float* fgam   = (const float*)d_in[19];
    const float* fbet   = (const float*)d_in[20];
    const float* fc1W   = (const float*)d_in[21];
    const float* fc1b   = (const float*)d_in[22];
    const float* d1a    = (const float*)d_in[23];
    const float* d1b    = (const float*)d_in[24];
    const float* fc2W   = (const float*)d_in[25];
    const float* fc2b   = (const float*)d_in[26];
    const float* d2a    = (const float*)d_in[27];
    const float* d2b    = (const float*)d_in[28];
    const float* fc3W   = (const float*)d_in[29];
    const float* fc3b   = (const float*)d_in[30];

    float* ws        = (float*)d_ws;
    float* hist_attn = ws;                    // 262144
    float* stats     = hist_attn + 262144;    // 1264
    float* hstats  = stats;                   // 256
    float* jstats  = stats + 256;             // 768
    float* p1stats = jstats + 768;            // 160
    float* p2stats = p1stats + 160;           // 80
    int*   bar     = (int*)(stats + 1264);    // 2 ints
    float* prep    = stats + 1268;            // 64640
    float* W1pair = prep;
    float* W1ac   = prep + 20480;
    float* fc1WT  = prep + 30720;
    float* fc2WT  = prep + 61440;

    hipMemsetAsync(stats, 0, 1268 * sizeof(float), stream);

    k0_prep<<<128, 256, 0, stream>>>(att_W1, fc1W, fc2W, prep);

    k1_attn<<<BB, 512, 0, stream>>>(item, history, length, cate_list,
        item_table, cate_table, W1pair, W1ac,
        att_b1, att_W2, att_b2, att_W3, att_b3,
        hist_attn, hstats);

    TailArgs ta;
    ta.hist_attn = hist_attn; ta.hstats = hstats;
    ta.hgamma = hgam; ta.hbeta = hbet; ta.histW = histW; ta.histb = histb;
    ta.user = user; ta.item = item; ta.cate_list = cate_list;
    ta.user_table = user_table; ta.item_table = item_table; ta.cate_table = cate_table;
    ta.jstats = jstats; ta.p1stats = p1stats; ta.p2stats = p2stats;
    ta.fgamma = fgam; ta.fbeta = fbet; ta.fc1WT = fc1WT; ta.fc1b = fc1b;
    ta.d1a = d1a; ta.d1b = d1b; ta.fc2WT = fc2WT; ta.fc2b = fc2b;
    ta.d2a = d2a; ta.d2b = d2b; ta.fc3W = fc3W; ta.fc3b = fc3b;
    ta.item_bias = item_bias; ta.outp = (float*)d_out;
    ta.bar = bar;

    k_tail<<<256, 256, 0, stream>>>(ta);
}

// Round 5
// 405.025 us; speedup vs baseline: 1.3864x; 1.2550x over previous
//
#include <hip/hip_runtime.h>
#include <math.h>

#define BB 2048
#define TT 200
#define BN_EPS 1e-3f
#define MASKV (-4294967295.0f)
#define INV_SQRTK 0.08838834764831845f

typedef short bfrag __attribute__((ext_vector_type(8)));
typedef float f32x4 __attribute__((ext_vector_type(4)));

__device__ __forceinline__ unsigned short f2b(float x) {
    union { float f; unsigned u; } v; v.f = x;
    unsigned r = (v.u + 0x7fffu + ((v.u >> 16) & 1u)) >> 16;
    return (unsigned short)r;
}
__device__ __forceinline__ float sigm(float x) { return 1.f / (1.f + __expf(-x)); }

// ---------------------------------------------------------------------------
// k0: weight prep (block-invariant).
// ---------------------------------------------------------------------------
__global__ __launch_bounds__(256) void k0_prep(
    const float* __restrict__ W1, const float* __restrict__ fc1W,
    const float* __restrict__ fc2W, float* __restrict__ prep)
{
    const int gid = blockIdx.x * 256 + threadIdx.x;
    const int stride = gridDim.x * 256;
    float* W1pair = prep;                 // 20480
    float* W1ac   = prep + 20480;         // 10240
    float* fc1WT  = prep + 30720;         // 30720
    float* fc2WT  = prep + 61440;         // 3200
    for (int i = gid; i < 10240; i += stride) {
        int j = i >> 7, k = i & 127;
        float wa = W1[k * 80 + j];
        float wb = W1[(128 + k) * 80 + j];
        float wc = W1[(256 + k) * 80 + j];
        float wd = W1[(384 + k) * 80 + j];
        W1pair[i * 2]     = wb - wc;
        W1pair[i * 2 + 1] = wd;
        W1ac[k * 80 + j]  = wa + wc;
    }
    for (int i = gid; i < 30720; i += stride) { int j = i / 384, c = i - j * 384; fc1WT[i] = fc1W[c * 80 + j]; }
    for (int i = gid; i < 3200;  i += stride) { int j = i / 80,  c = i - j * 80;  fc2WT[i] = fc2W[c * 40 + j]; }
}

// ---------------------------------------------------------------------------
// K1: DIN attention. 2048 blocks x 512 thr, ~81KB LDS -> 2 blocks/CU.
// R3 skeleton + static layer-2 (no scratch) + W2 via LDS + global-gather D.
// ---------------------------------------------------------------------------
__global__ __launch_bounds__(512, 4) void k1_attn(
    const int* __restrict__ item, const int* __restrict__ history,
    const int* __restrict__ length, const int* __restrict__ cate_list,
    const float* __restrict__ item_table, const float* __restrict__ cate_table,
    const float* __restrict__ W1pair, const float* __restrict__ W1ac,
    const float* __restrict__ b1, const float* __restrict__ W2,
    const float* __restrict__ b2, const float* __restrict__ W3,
    const float* __restrict__ b3,
    float* __restrict__ hist_attn, float* __restrict__ hstats8)
{
    __shared__ __align__(16) unsigned short sA[112 * 136];   // 30464 B
    __shared__ __align__(16) unsigned short sW1[80 * 136];   // 21760 B
    __shared__ __align__(16) unsigned short sH1[112 * 112];  // 25088 B (alias: sCp, sW2a, sPd)
    __shared__ float sScore[256];                            // alias: sQ
    __shared__ float sCc[80];
    __shared__ int   sHist[TT], sCid[TT];
    __shared__ float sB2[48], sW3f[48];
    __shared__ float sRed[8], sMS[2], sB3v;

    float* const sQ  = sScore;                               // 128 floats (dead before zeroing)
    float* const sCp = (float*)sH1;                          // 480 floats (shorts [0,960))
    unsigned short* const sW2a = sH1 + 1024;                 // [48][112] shorts [1024,6400)
    float* const sPd = (float*)sH1;                          // 16*128 floats, phase D

    const int b   = blockIdx.x;
    const int tid = threadIdx.x;
    const int it  = item[b];
    const int len = length[b];
    const int w = tid >> 6, l = tid & 63, lo16 = l & 15, hi = l >> 4;

    // ---- Phase A: lookups + stage W2 -> LDS bf16 [48][112] ----
    if (tid < 64)       sQ[tid] = item_table[(size_t)it * 64 + tid];
    else if (tid < 128) sQ[tid] = cate_table[(size_t)cate_list[it] * 64 + (tid - 64)];
    if (tid < TT) { int h = history[(size_t)b * TT + tid]; sHist[tid] = h; sCid[tid] = cate_list[h]; }
    if (tid < 48) { sB2[tid] = (tid < 40) ? b2[tid] : 0.f; sW3f[tid] = (tid < 40) ? W3[tid] : 0.f; }
    if (tid == 0) sB3v = b3[0];
    for (int i = tid; i < 48 * 112; i += 512) {
        int n = i / 112, k = i - n * 112;
        float v = (n < 40 && k < 80) ? W2[k * 40 + n] : 0.f;
        sW2a[i] = f2b(v);
    }
    __syncthreads();

    // ---- Phase B: W1eff build (pairs), c-partials, stage rows 0..111 ----
    for (int i = tid; i < 5120; i += 512) {
        int j = i >> 6, kh = (i & 63) * 2;
        float4 p = *(const float4*)&W1pair[(size_t)(j * 128 + kh) * 2];
        float2 q = *(const float2*)&sQ[kh];
        unsigned pk = (unsigned)f2b(p.x + q.x * p.y) | ((unsigned)f2b(p.z + q.y * p.w) << 16);
        *(unsigned*)&sW1[j * 136 + kh] = pk;
    }
    if (tid < 480) {
        int g = tid / 80, j = tid - g * 80;
        int k0 = g * 22, k1e = (k0 + 22 < 128) ? k0 + 22 : 128;
        float c = 0.f;
        for (int k = k0; k < k1e; ++k) c = fmaf(sQ[k], W1ac[k * 80 + j], c);
        sCp[tid] = c;
    }
    if (tid < 448) {
        int r = tid >> 2, s = tid & 3;
        unsigned short* dst = &sA[r * 136 + s * 32];
        const float* src = (s < 2) ? (item_table + (size_t)sHist[r] * 64 + s * 32)
                                   : (cate_table + (size_t)sCid[r] * 64 + (s - 2) * 32);
#pragma unroll
        for (int q4 = 0; q4 < 8; ++q4) {
            float4 v = ((const float4*)src)[q4];
            ushort4 o; o.x = f2b(v.x); o.y = f2b(v.y); o.z = f2b(v.z); o.w = f2b(v.w);
            *(ushort4*)(dst + q4 * 4) = o;
        }
    }
    __syncthreads();

    // ---- Phase C: sCc reduce ; zero scores ; load w2f frags from LDS ----
    if (tid < 80) {
        float c = b1[tid];
#pragma unroll
        for (int g = 0; g < 6; ++g) c += sCp[g * 80 + tid];
        sCc[tid] = c;
    }
    if (tid < 256) sScore[tid] = 0.f;
    bfrag w2f[3][3];
#pragma unroll
    for (int nt = 0; nt < 3; ++nt)
#pragma unroll
        for (int ks = 0; ks < 3; ++ks)
            w2f[nt][ks] = *(const bfrag*)&sW2a[(nt * 16 + lo16) * 112 + ks * 32 + hi * 8];
    __syncthreads();

    // ---- layer1 pass1: 7 Mt x 5 Nt ----
    f32x4 acc1[5];
#pragma unroll
    for (int pp = 0; pp < 5; ++pp) {
        int p = w + pp * 8;
        if (p < 35) {
            int mt = p / 5, nt = p - mt * 5;
            const unsigned short* Ab = &sA[(mt * 16 + lo16) * 136 + hi * 8];
            const unsigned short* Bb = &sW1[(nt * 16 + lo16) * 136 + hi * 8];
            f32x4 acc = {0.f, 0.f, 0.f, 0.f};
#pragma unroll
            for (int ks = 0; ks < 4; ++ks)
                acc = __builtin_amdgcn_mfma_f32_16x16x32_bf16(
                    *(const bfrag*)(Ab + ks * 32), *(const bfrag*)(Bb + ks * 32), acc, 0, 0, 0);
            acc1[pp] = acc;
        }
    }
    __syncthreads();   // sA reads done; sCp/sW2a dead -> sH1 writable

    // ---- sigmoid p1 -> sH1 [112][112] ; zero k-pads ; stage rows 112..207 ----
#pragma unroll
    for (int pp = 0; pp < 5; ++pp) {
        int p = w + pp * 8;
        if (p < 35) {
            int mt = p / 5, nt = p - mt * 5;
            int j = nt * 16 + lo16;
            float cc = sCc[j];
#pragma unroll
            for (int rg = 0; rg < 4; ++rg)
                sH1[(mt * 16 + hi * 4 + rg) * 112 + j] = f2b(sigm(acc1[pp][rg] + cc));
        }
    }
    for (int i = tid; i < 112 * 16; i += 512) sH1[(i >> 4) * 112 + 80 + (i & 15)] = 0;
    if (tid < 448) {
        int r = tid >> 2, s = tid & 3;
        int t = 112 + r;
        unsigned short* dst = &sA[r * 136 + s * 32];
        if (t < TT) {
            const float* src = (s < 2) ? (item_table + (size_t)sHist[t] * 64 + s * 32)
                                       : (cate_table + (size_t)sCid[t] * 64 + (s - 2) * 32);
#pragma unroll
            for (int q4 = 0; q4 < 8; ++q4) {
                float4 v = ((const float4*)src)[q4];
                ushort4 o; o.x = f2b(v.x); o.y = f2b(v.y); o.z = f2b(v.z); o.w = f2b(v.w);
                *(ushort4*)(dst + q4 * 4) = o;
            }
        } else {
            ushort4 z = {0, 0, 0, 0};
#pragma unroll
            for (int q4 = 0; q4 < 8; ++q4) *(ushort4*)(dst + q4 * 4) = z;
        }
    }
    __syncthreads();

    // ---- layer2 pass1 (static: wave w<7 owns mt=w) then layer1 pass2 ----
    if (w < 7) {
        bfrag af[3];
        const unsigned short* Ab = &sH1[(w * 16 + lo16) * 112 + hi * 8];
#pragma unroll
        for (int ks = 0; ks < 3; ++ks) af[ks] = *(const bfrag*)(Ab + ks * 32);
#pragma unroll
        for (int nt = 0; nt < 3; ++nt) {
            f32x4 acc = {0.f, 0.f, 0.f, 0.f};
#pragma unroll
            for (int ks = 0; ks < 3; ++ks)
                acc = __builtin_amdgcn_mfma_f32_16x16x32_bf16(af[ks], w2f[nt][ks], acc, 0, 0, 0);
            int j2 = nt * 16 + lo16;
            float w3 = sW3f[j2], b2v = sB2[j2];
#pragma unroll
            for (int rg = 0; rg < 4; ++rg) {
                float pt = sigm(acc[rg] + b2v) * w3;
                pt += __shfl_xor(pt, 1);
                pt += __shfl_xor(pt, 2);
                pt += __shfl_xor(pt, 4);
                pt += __shfl_xor(pt, 8);
                if (lo16 == 0) atomicAdd(&sScore[w * 16 + hi * 4 + rg], pt);
            }
        }
    }
    f32x4 acc2[5];
#pragma unroll
    for (int pp = 0; pp < 5; ++pp) {
        int p = w + pp * 8;
        if (p < 35) {
            int mt = p / 5, nt = p - mt * 5;
            const unsigned short* Ab = &sA[(mt * 16 + lo16) * 136 + hi * 8];
            const unsigned short* Bb = &sW1[(nt * 16 + lo16) * 136 + hi * 8];
            f32x4 acc = {0.f, 0.f, 0.f, 0.f};
#pragma unroll
            for (int ks = 0; ks < 4; ++ks)
                acc = __builtin_amdgcn_mfma_f32_16x16x32_bf16(
                    *(const bfrag*)(Ab + ks * 32), *(const bfrag*)(Bb + ks * 32), acc, 0, 0, 0);
            acc2[pp] = acc;
        }
    }
    __syncthreads();   // sH1 reads done

    // ---- sigmoid p2 -> sH1 (pads persist) ----
#pragma unroll
    for (int pp = 0; pp < 5; ++pp) {
        int p = w + pp * 8;
        if (p < 35) {
            int mt = p / 5, nt = p - mt * 5;
            int j = nt * 16 + lo16;
            float cc = sCc[j];
#pragma unroll
            for (int rg = 0; rg < 4; ++rg)
                sH1[(mt * 16 + hi * 4 + rg) * 112 + j] = f2b(sigm(acc2[pp][rg] + cc));
        }
    }
    __syncthreads();

    // ---- layer2 pass2 (static) ----
    if (w < 7) {
        bfrag af[3];
        const unsigned short* Ab = &sH1[(w * 16 + lo16) * 112 + hi * 8];
#pragma unroll
        for (int ks = 0; ks < 3; ++ks) af[ks] = *(const bfrag*)(Ab + ks * 32);
#pragma unroll
        for (int nt = 0; nt < 3; ++nt) {
            f32x4 acc = {0.f, 0.f, 0.f, 0.f};
#pragma unroll
            for (int ks = 0; ks < 3; ++ks)
                acc = __builtin_amdgcn_mfma_f32_16x16x32_bf16(af[ks], w2f[nt][ks], acc, 0, 0, 0);
            int j2 = nt * 16 + lo16;
            float w3 = sW3f[j2], b2v = sB2[j2];
#pragma unroll
            for (int rg = 0; rg < 4; ++rg) {
                float pt = sigm(acc[rg] + b2v) * w3;
                pt += __shfl_xor(pt, 1);
                pt += __shfl_xor(pt, 2);
                pt += __shfl_xor(pt, 4);
                pt += __shfl_xor(pt, 8);
                if (lo16 == 0) atomicAdd(&sScore[112 + w * 16 + hi * 4 + rg], pt);
            }
        }
    }
    __syncthreads();

    // ---- softmax over T ----
    int t = tid;
    float sc;
    if (t < TT) {
        float raw = sScore[t] + sB3v;
        if (t >= len) raw = MASKV;
        sc = raw * INV_SQRTK;
    } else {
        sc = -3.0e38f;
    }
    float mx = sc;
#pragma unroll
    for (int o = 32; o > 0; o >>= 1) mx = fmaxf(mx, __shfl_xor(mx, o));
    if ((tid & 63) == 0) sRed[tid >> 6] = mx;
    __syncthreads();
    if (tid == 0) {
        float m2 = sRed[0];
        for (int ww = 1; ww < 8; ++ww) m2 = fmaxf(m2, sRed[ww]);
        sMS[0] = m2;
    }
    __syncthreads();
    mx = sMS[0];
    float e = (t < TT) ? __expf(sc - mx) : 0.f;
    float sum = e;
#pragma unroll
    for (int o = 32; o > 0; o >>= 1) sum += __shfl_xor(sum, o);
    if ((tid & 63) == 0) sRed[tid >> 6] = sum;
    __syncthreads();
    if (tid == 0) {
        float s2 = 0.f;
        for (int ww = 0; ww < 8; ++ww) s2 += sRed[ww];
        sMS[1] = s2;
    }
    __syncthreads();
    float inv = 1.f / sMS[1];
    if (t < TT) sScore[t] = e * inv;
    __syncthreads();

    // ---- Phase D: hist_attn = attn @ H (global f32 gather, L3-resident) ----
    {
        const int rg = tid >> 5, c4 = tid & 31;
        f32x4 ad = {0.f, 0.f, 0.f, 0.f};
        for (int tt = rg; tt < TT; tt += 16) {
            float aw = sScore[tt];
            const float* p = (c4 < 16) ? (item_table + (size_t)sHist[tt] * 64 + c4 * 4)
                                       : (cate_table + (size_t)sCid[tt] * 64 + (c4 - 16) * 4);
            float4 v = *(const float4*)p;
            ad[0] = fmaf(aw, v.x, ad[0]);
            ad[1] = fmaf(aw, v.y, ad[1]);
            ad[2] = fmaf(aw, v.z, ad[2]);
            ad[3] = fmaf(aw, v.w, ad[3]);
        }
        *(f32x4*)&sPd[rg * 128 + c4 * 4] = ad;
    }
    __syncthreads();
    if (tid < 128) {
        float tot = 0.f;
#pragma unroll
        for (int gg = 0; gg < 16; ++gg) tot += sPd[gg * 128 + tid];
        hist_attn[(size_t)b * 128 + tid] = tot;
        float* hs = hstats8 + (size_t)(b & 7) * 256;
        atomicAdd(&hs[tid], tot);
        atomicAdd(&hs[128 + tid], tot * tot);
    }
}

// ---------------------------------------------------------------------------
// k_tail: fused BN chain. 256 blocks x 1024 threads (16 waves/CU), manual
// grid barrier with s_sleep backoff; all stats via 8-sliced atomics.
// ---------------------------------------------------------------------------
struct TailArgs {
    const float *hist_attn, *hstats8;
    const float *hgamma, *hbeta, *histW, *histb;
    const int *user, *item, *cate_list;
    const float *user_table, *item_table, *cate_table;
    float *jstats8, *p1stats8, *p2stats8;
    const float *fgamma, *fbeta, *fc1WT, *fc1b, *d1a, *d1b;
    const float *fc2WT, *fc2b, *d2a, *d2b, *fc3W, *fc3b, *item_bias;
    float *outp;
    int *bar;   // [counter, gen], zeroed each launch
};

__device__ __forceinline__ void gbar(int* bar, int nb) {
    __syncthreads();
    if (threadIdx.x == 0) {
        __threadfence();
        int g = __hip_atomic_load(bar + 1, __ATOMIC_RELAXED, __HIP_MEMORY_SCOPE_AGENT);
        int t = __hip_atomic_fetch_add(bar, 1, __ATOMIC_ACQ_REL, __HIP_MEMORY_SCOPE_AGENT);
        if (t == nb - 1) {
            __hip_atomic_store(bar, 0, __ATOMIC_RELAXED, __HIP_MEMORY_SCOPE_AGENT);
            __hip_atomic_fetch_add(bar + 1, 1, __ATOMIC_RELEASE, __HIP_MEMORY_SCOPE_AGENT);
        } else {
            while (__hip_atomic_load(bar + 1, __ATOMIC_ACQUIRE, __HIP_MEMORY_SCOPE_AGENT) == g)
                __builtin_amdgcn_s_sleep(8);
        }
        __threadfence();
    }
    __syncthreads();
}

__global__ __launch_bounds__(1024) void k_tail(TailArgs a)
{
    __shared__ float sWs[128 * 132];       // 67584B ; stage B alias: sXn[8][388]
    __shared__ float sJoin[8 * 388];
    __shared__ float sX[8 * 132];          // stage A rows ; C alias sX1[8][84] ; D alias sD
    __shared__ float sHsum[256], sJsum[768];
    __shared__ float sScaleH[128], sShiftH[128], sCb[128];
    __shared__ float sCsP[8][128];
    __shared__ float sScaleJ[384], sShiftJ[384];
    __shared__ float sPre1[8 * 84];
    __shared__ float sPre2[8 * 44];
    __shared__ float sP1s[160], sP2s[80];
    __shared__ float sM1[80], sRs1[80], sA1[80], sBt1[80];
    __shared__ float sM2[40], sRs2[40], sA2[40], sBt2[40], sW3t[40];
    __shared__ float sB3t;

    float* const sXn = sWs;
    float* const sX1 = sX;
    float* const sD  = sX;

    const int tid = threadIdx.x;
    const int r0  = blockIdx.x * 8;
    const int sl  = blockIdx.x & 7;

    // ================= Stage A: hist BN + hist_fc + join + jstats ==========
    if (tid < 256) {
        float s = 0.f;
#pragma unroll
        for (int s8 = 0; s8 < 8; ++s8) s += a.hstats8[s8 * 256 + tid];
        sHsum[tid] = s;
    }
    __syncthreads();
    if (tid < 128) {
        float m  = sHsum[tid] * (1.f / 2048.f);
        float v  = sHsum[128 + tid] * (1.f / 2048.f) - m * m;
        float rs = rsqrtf(v + BN_EPS);
        float scv = a.hgamma[tid] * rs;
        sScaleH[tid] = scv;
        sShiftH[tid] = a.hbeta[tid] - m * scv;
        sCb[tid] = a.histb[tid];
    }
    __syncthreads();
    for (int i = tid; i < 128 * 128; i += 1024) {
        int k = i >> 7;
        sWs[k * 132 + (i & 127)] = sScaleH[k] * a.histW[i];
    }
    {
        int g = tid >> 7, j = tid & 127;
        float c = 0.f;
        for (int k = g * 16; k < g * 16 + 16; ++k) c = fmaf(sShiftH[k], a.histW[k * 128 + j], c);
        sCsP[g][j] = c;
    }
    {
        int r = tid >> 7, j = tid & 127;
        sX[r * 132 + j] = a.hist_attn[(size_t)(r0 + r) * 128 + j];
    }
    __syncthreads();
    {
        const int r = tid >> 7, j = tid & 127;
        float o = sCb[j];
#pragma unroll
        for (int g = 0; g < 8; ++g) o += sCsP[g][j];
        for (int k = 0; k < 128; ++k) o = fmaf(sX[r * 132 + k], sWs[k * 132 + j], o);
        int row = r0 + r;
        float ue = a.user_table[(size_t)a.user[row] * 128 + j];
        int itv  = a.item[row];
        float qv = (j < 64) ? a.item_table[(size_t)itv * 64 + j]
                            : a.cate_table[(size_t)a.cate_list[itv] * 64 + (j - 64)];
        sJoin[r * 388 + j]       = ue;
        sJoin[r * 388 + 128 + j] = qv;
        sJoin[r * 388 + 256 + j] = o;
    }
    __syncthreads();
    if (tid < 768) {
        float s = 0.f;
        if (tid < 384) {
            for (int r = 0; r < 8; ++r) s += sJoin[r * 388 + tid];
        } else {
            int cc = tid - 384;
            for (int r = 0; r < 8; ++r) { float v = sJoin[r * 388 + cc]; s = fmaf(v, v, s); }
        }
        atomicAdd(&a.jstats8[sl * 768 + tid], s);
    }
    gbar(a.bar, 256);

    // ================= Stage B: BN(join) + fc1 + p1stats ===================
    if (tid < 768) {
        float s = 0.f;
#pragma unroll
        for (int s8 = 0; s8 < 8; ++s8) s += a.jstats8[s8 * 768 + tid];
        sJsum[tid] = s;
    }
    __syncthreads();
    if (tid < 384) {
        float m  = sJsum[tid] * (1.f / 2048.f);
        float v  = sJsum[384 + tid] * (1.f / 2048.f) - m * m;
        float rs = rsqrtf(v + BN_EPS);
        float scv = a.fgamma[tid] * rs;
        sScaleJ[tid] = scv;
        sShiftJ[tid] = a.fbeta[tid] - m * scv;
    }
    __syncthreads();
    for (int i = tid; i < 8 * 384; i += 1024) {
        int r = i / 384, c = i - r * 384;
        sXn[r * 388 + c] = sJoin[r * 388 + c] * sScaleJ[c] + sShiftJ[c];
    }
    __syncthreads();
    if (tid < 640) {
        int r = tid / 80, j = tid - (tid / 80) * 80;
        const float* wrow = a.fc1WT + (size_t)j * 384;
        float acc = a.fc1b[j];
        for (int c = 0; c < 384; c += 4) {
            float4 wv = *(const float4*)(wrow + c);
            float4 xv = *(const float4*)&sXn[r * 388 + c];
            acc = fmaf(wv.x, xv.x, fmaf(wv.y, xv.y, fmaf(wv.z, xv.z, fmaf(wv.w, xv.w, acc))));
        }
        sPre1[r * 84 + j] = acc;
    }
    __syncthreads();
    if (tid < 160) {
        int c = tid & 127; if (tid >= 80) c = tid - 80;
        int kind = tid / 80;
        float s = 0.f;
        for (int r = 0; r < 8; ++r) {
            float v = sPre1[r * 84 + c];
            s += kind ? v * v : v;
        }
        atomicAdd(&a.p1stats8[sl * 160 + tid], s);
    }
    gbar(a.bar, 256);

    // ================= Stage C: dice1 + fc2 + p2stats ======================
    if (tid < 160) {
        float s = 0.f;
#pragma unroll
        for (int s8 = 0; s8 < 8; ++s8) s += a.p1stats8[s8 * 160 + tid];
        sP1s[tid] = s;
    }
    __syncthreads();
    if (tid < 80) {
        float m = sP1s[tid] * (1.f / 2048.f);
        float v = sP1s[80 + tid] * (1.f / 2048.f) - m * m;
        sM1[tid]  = m;
        sRs1[tid] = rsqrtf(v + BN_EPS);
        sA1[tid]  = a.d1a[tid];
        sBt1[tid] = a.d1b[tid];
    }
    __syncthreads();
    if (tid < 640) {
        int r = tid / 80, c = tid - (tid / 80) * 80;
        float x  = sPre1[r * 84 + c];
        float xn = (x - sM1[c]) * sRs1[c];
        float p  = sigm(sBt1[c] * xn);
        sX1[r * 84 + c] = x * (p + sA1[c] * (1.f - p));
    }
    __syncthreads();
    if (tid < 320) {
        int r = tid / 40, j = tid - (tid / 40) * 40;
        const float* wrow = a.fc2WT + (size_t)j * 80;
        float acc = a.fc2b[j];
        for (int c = 0; c < 80; c += 4) {
            float4 wv = *(const float4*)(wrow + c);
            float4 xv = *(const float4*)&sX1[r * 84 + c];
            acc = fmaf(wv.x, xv.x, fmaf(wv.y, xv.y, fmaf(wv.z, xv.z, fmaf(wv.w, xv.w, acc))));
        }
        sPre2[r * 44 + j] = acc;
    }
    __syncthreads();
    if (tid < 80) {
        int c = (tid < 40) ? tid : tid - 40;
        int kind = tid / 40;
        float s = 0.f;
        for (int r = 0; r < 8; ++r) {
            float v = sPre2[r * 44 + c];
            s += kind ? v * v : v;
        }
        atomicAdd(&a.p2stats8[sl * 80 + tid], s);
    }
    gbar(a.bar, 256);

    // ================= Stage D: dice2 + fc3 + bias + sigmoid ===============
    if (tid < 80) {
        float s = 0.f;
#pragma unroll
        for (int s8 = 0; s8 < 8; ++s8) s += a.p2stats8[s8 * 80 + tid];
        sP2s[tid] = s;
    }
    __syncthreads();
    if (tid < 40) {
        float m = sP2s[tid] * (1.f / 2048.f);
        float v = sP2s[40 + tid] * (1.f / 2048.f) - m * m;
        sM2[tid]  = m;
        sRs2[tid] = rsqrtf(v + BN_EPS);
        sA2[tid]  = a.d2a[tid];
        sBt2[tid] = a.d2b[tid];
        sW3t[tid] = a.fc3W[tid];
    }
    if (tid == 0) sB3t = a.fc3b[0];
    __syncthreads();
    if (tid < 320) {
        int r = tid / 40, c = tid - (tid / 40) * 40;
        float x  = sPre2[r * 44 + c];
        float xn = (x - sM2[c]) * sRs2[c];
        float p  = sigm(sBt2[c] * xn);
        sD[r * 40 + c] = x * (p + sA2[c] * (1.f - p)) * sW3t[c];
    }
    __syncthreads();
    if (tid < 8) {
        float s = sB3t;
        for (int c = 0; c < 40; ++c) s += sD[tid * 40 + c];
        int row = r0 + tid;
        float v = s + a.item_bias[a.item[row]];
        a.outp[row]      = v;
        a.outp[BB + row] = sigm(v);
    }
}

// ---------------------------------------------------------------------------
extern "C" void kernel_launch(void* const* d_in, const int* in_sizes, int n_in,
                              void* d_out, int out_size, void* d_ws, size_t ws_size,
                              hipStream_t stream)
{
    const int*   user       = (const int*)d_in[0];
    const int*   item       = (const int*)d_in[1];
    const int*   history    = (const int*)d_in[2];
    const int*   length     = (const int*)d_in[3];
    const int*   cate_list  = (const int*)d_in[4];
    const float* user_table = (const float*)d_in[5];
    const float* item_table = (const float*)d_in[6];
    const float* cate_table = (const float*)d_in[7];
    const float* item_bias  = (const float*)d_in[8];
    const float* att_W1 = (const float*)d_in[9];
    const float* att_b1 = (const float*)d_in[10];
    const float* att_W2 = (const float*)d_in[11];
    const float* att_b2 = (const float*)d_in[12];
    const float* att_W3 = (const float*)d_in[13];
    const float* att_b3 = (const float*)d_in[14];
    const float* hgam   = (const float*)d_in[15];
    const float* hbet   = (const float*)d_in[16];
    const float* histW  = (const float*)d_in[17];
    const float* histb  = (const float*)d_in[18];
    const float* fgam   = (const float*)d_in[19];
    const float* fbet   = (const float*)d_in[20];
    const float* fc1W   = (const float*)d_in[21];
    const float* fc1b   = (const float*)d_in[22];
    const float* d1a    = (const float*)d_in[23];
    const float* d1b    = (const float*)d_in[24];
    const float* fc2W   = (const float*)d_in[25];
    const float* fc2b   = (const float*)d_in[26];
    const float* d2a    = (const float*)d_in[27];
    const float* d2b    = (const float*)d_in[28];
    const float* fc3W   = (const float*)d_in[29];
    const float* fc3b   = (const float*)d_in[30];

    float* ws        = (float*)d_ws;
    float* hist_attn = ws;                    // 262144
    float* stats     = hist_attn + 262144;
    float* hstats8   = stats;                 // 8*256  = 2048
    float* jstats8   = hstats8 + 2048;        // 8*768  = 6144
    float* p1stats8  = jstats8 + 6144;        // 8*160  = 1280
    float* p2stats8  = p1stats8 + 1280;       // 8*80   = 640
    int*   bar       = (int*)(p2stats8 + 640);// 2
    float* prep      = p2stats8 + 644;        // 64640
    float* W1pair = prep;
    float* W1ac   = prep + 20480;
    float* fc1WT  = prep + 30720;
    float* fc2WT  = prep + 61440;

    hipMemsetAsync(stats, 0, (2048 + 6144 + 1280 + 640 + 4) * sizeof(float), stream);

    k0_prep<<<128, 256, 0, stream>>>(att_W1, fc1W, fc2W, prep);

    k1_attn<<<BB, 512, 0, stream>>>(item, history, length, cate_list,
        item_table, cate_table, W1pair, W1ac,
        att_b1, att_W2, att_b2, att_W3, att_b3,
        hist_attn, hstats8);

    TailArgs ta;
    ta.hist_attn = hist_attn; ta.hstats8 = hstats8;
    ta.hgamma = hgam; ta.hbeta = hbet; ta.histW = histW; ta.histb = histb;
    ta.user = user; ta.item = item; ta.cate_list = cate_list;
    ta.user_table = user_table; ta.item_table = item_table; ta.cate_table = cate_table;
    ta.jstats8 = jstats8; ta.p1stats8 = p1stats8; ta.p2stats8 = p2stats8;
    ta.fgamma = fgam; ta.fbeta = fbet; ta.fc1WT = fc1WT; ta.fc1b = fc1b;
    ta.d1a = d1a; ta.d1b = d1b; ta.fc2WT = fc2WT; ta.fc2b = fc2b;
    ta.d2a = d2a; ta.d2b = d2b; ta.fc3W = fc3W; ta.fc3b = fc3b;
    ta.item_bias = item_bias; ta.outp = (float*)d_out;
    ta.bar = bar;

    k_tail<<<256, 1024, 0, stream>>>(ta);
}